// Round 6
// baseline (57.960 us; speedup 1.0000x reference)
//
#include <hip/hip_runtime.h>

typedef unsigned long long u64;
typedef unsigned int u32;

#define B_  32
#define S_  1024
#define K_  16
#define NTK 256     // threads/block
#define QPB 32      // queries per block (NTK/8)
#define CAP 26      // per-lane collected-index capacity (16 + tie headroom)

// ---------- f32 compare-exchange (v_min_f32 + v_max_f32, full rate) ----------
__device__ __forceinline__ void cef(float& a, float& b) {
    const float lo = fminf(a, b);
    const float hi = fmaxf(a, b);
    a = lo; b = hi;
}

// Batcher odd-even mergesort of 8 f32, 19 CE, ascending (network proven in r4)
__device__ __forceinline__ void sort8f(float (&k)[8]) {
    cef(k[0], k[1]); cef(k[2], k[3]); cef(k[4], k[5]); cef(k[6], k[7]);
    cef(k[0], k[2]); cef(k[1], k[3]); cef(k[4], k[6]); cef(k[5], k[7]);
    cef(k[1], k[2]); cef(k[5], k[6]);
    cef(k[0], k[4]); cef(k[1], k[5]); cef(k[2], k[6]); cef(k[3], k[7]);
    cef(k[2], k[4]); cef(k[3], k[5]);
    cef(k[1], k[2]); cef(k[3], k[4]); cef(k[5], k[6]);
}

// clean a bitonic f32 16-sequence into ascending order (32 CE)
__device__ __forceinline__ void clean16f(float (&k)[16]) {
#pragma unroll
    for (int str = 8; str > 0; str >>= 1) {
#pragma unroll
        for (int t = 0; t < 16; ++t) {
            const int p = t ^ str;
            if (p > t) cef(k[t], k[p]);
        }
    }
}

// ---------- f64 packed (d2,j) keys for the exact final ordering ----------
// key = double bit pattern (d2_f32_bits << 32) | j ; d2 >= 0 -> positive
// finite double, so IEEE fmin/fmax order keys exactly as u64 (ties -> lower j).
__device__ __forceinline__ double pack_key(float d2, int j) {
    return __longlong_as_double(((u64)__float_as_uint(d2) << 32) | (u32)j);
}

__device__ __forceinline__ void ce(double& a, double& b) {
    const double lo = fmin(a, b);
    const double hi = fmax(a, b);
    a = lo; b = hi;
}

// full bitonic ascending sort of 16 f64 keys (once per lane)
__device__ __forceinline__ void sort16d(double (&k)[16]) {
#pragma unroll
    for (int size = 2; size <= 16; size <<= 1) {
#pragma unroll
        for (int str = size >> 1; str > 0; str >>= 1) {
#pragma unroll
            for (int t = 0; t < 16; ++t) {
                const int p = t ^ str;
                if (p > t) {
                    if ((t & size) == 0) ce(k[t], k[p]);
                    else                 ce(k[p], k[t]);
                }
            }
        }
    }
}

// clean a bitonic f64 16-sequence into ascending order (32 CE)
__device__ __forceinline__ void clean16d(double (&k)[16]) {
#pragma unroll
    for (int str = 8; str > 0; str >>= 1) {
#pragma unroll
        for (int t = 0; t < 16; ++t) {
            const int p = t ^ str;
            if (p > t) ce(k[t], k[p]);
        }
    }
}

__global__ __launch_bounds__(NTK, 3)
void knn_fused(const float* __restrict__ pos, const float* __restrict__ x,
               const float* __restrict__ Wm, const float* __restrict__ bv,
               float* __restrict__ out) {
    __shared__ float4 spos[S_];               // 16 KB
    __shared__ u32    jbuf[(CAP + 1) * NTK];  // 27 KB: [row][tid], row CAP = dump
    // total LDS 43 KB -> exactly 3 blocks/CU -> keeps 1.33-round write overlap

    const int tid   = threadIdx.x;
    const int cloud = blockIdx.x >> 5;        // 32 blocks per cloud
    const int qbase = (blockIdx.x & 31) * QPB;
    const int base  = cloud * S_;

    for (int r = tid; r < S_; r += NTK) {
        const float* p = pos + (size_t)(base + r) * 3;
        spos[r] = make_float4(p[0], p[1], p[2], 0.0f);
    }
    __syncthreads();

    const int s  = tid & 7;                   // slice: j = s (mod 8)
    const int qi = qbase + (tid >> 3);        // query within cloud
    const float4 pi = spos[qi];
    const float pix = pi.x, piy = pi.y, piz = pi.z;

    // ---- phase 1: f32-only scan, exact per-lane 16th-smallest d2 ----
    float keyf[16];
#pragma unroll
    for (int t = 0; t < 16; ++t) keyf[t] = __int_as_float(0x7F800000);  // +inf

    const float4* sp = &spos[s];              // lane slice, stride 8 float4
    float4 buf[8];
#pragma unroll
    for (int u = 0; u < 8; ++u) buf[u] = sp[8 * u];

    for (int c = 0; c < 16; ++c) {            // 16 chunks x 8 candidates
        float nk[8];
#pragma unroll
        for (int u = 0; u < 8; ++u) {
            // bit-exact numpy chain: no fma, (dx2+dy2)+dz2
            const float dx = __fsub_rn(pix, buf[u].x);
            const float dy = __fsub_rn(piy, buf[u].y);
            const float dz = __fsub_rn(piz, buf[u].z);
            nk[u] = __fadd_rn(
                __fadd_rn(__fmul_rn(dx, dx), __fmul_rn(dy, dy)),
                __fmul_rn(dz, dz));
        }
        if (c < 15) {                         // prefetch next chunk during sort
            sp += 64;
#pragma unroll
            for (int u = 0; u < 8; ++u) buf[u] = sp[8 * u];
        }
        sort8f(nk);
#pragma unroll
        for (int t = 0; t < 8; ++t)           // keep-16-smallest half-merge
            keyf[8 + t] = fminf(keyf[8 + t], nk[7 - t]);
        clean16f(keyf);
    }
    const float kth = keyf[15];               // exact 16th smallest of the lane

    // ---- phase 2: recollect indices with d2 <= kth (>=16 guaranteed) ----
    u32 fcnt = 0;
    {
        const float4* sp2 = &spos[s];
        float4 rbuf[8];
#pragma unroll
        for (int u = 0; u < 8; ++u) rbuf[u] = sp2[8 * u];
        int jr = s;
        for (int c = 0; c < 16; ++c) {
#pragma unroll
            for (int u = 0; u < 8; ++u) {
                const float dx = __fsub_rn(pix, rbuf[u].x);
                const float dy = __fsub_rn(piy, rbuf[u].y);
                const float dz = __fsub_rn(piz, rbuf[u].z);
                const float d2 = __fadd_rn(
                    __fadd_rn(__fmul_rn(dx, dx), __fmul_rn(dy, dy)),
                    __fmul_rn(dz, dz));
                const bool adm = (d2 <= kth) && (fcnt < CAP);
                const u32 row = adm ? fcnt : CAP;      // dump slot if not admitted
                jbuf[row * NTK + tid] = (u32)(jr + 8 * u);
                fcnt += adm ? 1u : 0u;
            }
            if (c < 15) {
                sp2 += 64;
#pragma unroll
                for (int u = 0; u < 8; ++u) rbuf[u] = sp2[8 * u];
            }
            jr += 64;
        }
    }

    // ---- phase 3: exact (d2,j) keys for the collected 16, f64 sort once ----
    double kd[16];
#pragma unroll
    for (int t = 0; t < 16; ++t) {
        const u32 jl = jbuf[t * NTK + tid];   // rows 0..15 always valid
        const float4 pj = spos[jl];
        const float dx = __fsub_rn(pix, pj.x);
        const float dy = __fsub_rn(piy, pj.y);
        const float dz = __fsub_rn(piz, pj.z);
        const float d2 = __fadd_rn(
            __fadd_rn(__fmul_rn(dx, dx), __fmul_rn(dy, dy)),
            __fmul_rn(dz, dz));
        kd[t] = pack_key(d2, (int)jl);
    }
    sort16d(kd);
    // rare tie-extras (fcnt > 16): replace-max then bitonic clean, exec-masked
    for (int t = 16; t < (int)fcnt; ++t) {
        const u32 jl = jbuf[t * NTK + tid];
        const float4 pj = spos[jl];
        const float dx = __fsub_rn(pix, pj.x);
        const float dy = __fsub_rn(piy, pj.y);
        const float dz = __fsub_rn(piz, pj.z);
        const float d2 = __fadd_rn(
            __fadd_rn(__fmul_rn(dx, dx), __fmul_rn(dy, dy)),
            __fmul_rn(dz, dz));
        kd[15] = fmin(kd[15], pack_key(d2, (int)jl));
        clean16d(kd);                         // sorted15+1 is bitonic -> sorted
    }

    // ---- butterfly merge across the 8 slice lanes (all end identical) ----
#pragma unroll
    for (int r = 1; r <= 4; r <<= 1) {
        double nk[16];
#pragma unroll
        for (int t = 0; t < 16; ++t)
            nk[t] = __shfl_xor(kd[15 - t], r, 64);   // reversed partner list
#pragma unroll
        for (int t = 0; t < 16; ++t)
            kd[t] = fmin(kd[t], nk[t]);              // stride-16 half-cleaner
        clean16d(kd);
    }

    // ---- fused epilogue: 8 lanes emit the query's 16 output rows ----
    const float4* x4 = (const float4*)x;
    const float4* W4 = (const float4*)Wm;     // W[10][32]: row = 8 float4
    float4 wcol[10];
#pragma unroll
    for (int m = 0; m < 10; ++m) wcol[m] = W4[m * 8 + s];
    const float4 bb = ((const float4*)bv)[s];

    float4* orow = (float4*)out + (size_t)(base + qi) * (K_ * 16);
#pragma unroll
    for (int k = 0; k < 16; ++k) {
        const int jl = (int)(u32)__double_as_longlong(kd[k]);    // local j
        const float4 xj = x4[(size_t)(base + jl) * 8 + s];       // coalesced
        const float4 pj = spos[jl];                              // broadcast
        const float rx = pix - pj.x, ry = piy - pj.y, rz = piz - pj.z;
        const float dist = sqrtf(rx * rx + ry * ry + rz * rz + 1e-12f);
        const float f[10] = {pix, piy, piz, pj.x, pj.y, pj.z, rx, ry, rz, dist};
        float4 acc = bb;
#pragma unroll
        for (int m = 0; m < 10; ++m) {
            acc.x = fmaf(f[m], wcol[m].x, acc.x);
            acc.y = fmaf(f[m], wcol[m].y, acc.y);
            acc.z = fmaf(f[m], wcol[m].z, acc.z);
            acc.w = fmaf(f[m], wcol[m].w, acc.w);
        }
        acc.x = fmaxf(acc.x, 0.0f);
        acc.y = fmaxf(acc.y, 0.0f);
        acc.z = fmaxf(acc.z, 0.0f);
        acc.w = fmaxf(acc.w, 0.0f);
        orow[k * 16 + s]     = xj;
        orow[k * 16 + 8 + s] = acc;
    }
}

extern "C" void kernel_launch(void* const* d_in, const int* in_sizes, int n_in,
                              void* d_out, int out_size, void* d_ws, size_t ws_size,
                              hipStream_t stream) {
    const float* x   = (const float*)d_in[0];
    const float* pos = (const float*)d_in[1];
    // d_in[2] = batch (unused: equal-size contiguous clouds)
    const float* Wm  = (const float*)d_in[3];
    const float* bv  = (const float*)d_in[4];
    float* out = (float*)d_out;

    knn_fused<<<B_ * 32, NTK, 0, stream>>>(pos, x, Wm, bv, out);
}

// Round 7
// 51.256 us; speedup vs baseline: 1.1308x; 1.1308x over previous
//
#include <hip/hip_runtime.h>

typedef unsigned long long u64;
typedef unsigned int u32;

#define B_  32
#define S_  1024
#define K_  16
#define NTK 64      // threads/block = 1 wave
#define QPB 8       // queries per block (NTK/8)

// key = double whose bit pattern is (d2_f32_bits << 32) | j.
// d2 >= 0 -> high word in [0, 0x7F7FFFFF] -> positive finite double,
// so IEEE fmin/fmax (v_min_f64/v_max_f64) order keys exactly as u64.
__device__ __forceinline__ double pack_key(float d2, int j) {
    return __longlong_as_double(((u64)__float_as_uint(d2) << 32) | (u32)j);
}

// ascending compare-exchange: 2 VALU instrs
__device__ __forceinline__ void ce(double& a, double& b) {
    const double lo = fmin(a, b);
    const double hi = fmax(a, b);
    a = lo; b = hi;
}

// Batcher odd-even mergesort of 8 keys, 19 CE, depth 6, ascending
__device__ __forceinline__ void sort8(double (&k)[8]) {
    ce(k[0], k[1]); ce(k[2], k[3]); ce(k[4], k[5]); ce(k[6], k[7]);
    ce(k[0], k[2]); ce(k[1], k[3]); ce(k[4], k[6]); ce(k[5], k[7]);
    ce(k[1], k[2]); ce(k[5], k[6]);
    ce(k[0], k[4]); ce(k[1], k[5]); ce(k[2], k[6]); ce(k[3], k[7]);
    ce(k[2], k[4]); ce(k[3], k[5]);
    ce(k[1], k[2]); ce(k[3], k[4]); ce(k[5], k[6]);
}

// clean a bitonic 16-sequence into ascending order (4 stages, 32 CE)
__device__ __forceinline__ void clean16(double (&k)[16]) {
#pragma unroll
    for (int str = 8; str > 0; str >>= 1) {
#pragma unroll
        for (int t = 0; t < 16; ++t) {
            const int p = t ^ str;
            if (p > t) ce(k[t], k[p]);
        }
    }
}

__global__ __launch_bounds__(NTK, 4)
void knn_fused(const float* __restrict__ pos, const float* __restrict__ x,
               const float* __restrict__ Wm, const float* __restrict__ bv,
               float* __restrict__ out) {
    __shared__ float4 spos[S_];             // 16 KB -> 10 blocks/CU (LDS-limited)

    const int tid   = threadIdx.x;
    const int cloud = blockIdx.x >> 7;      // 128 blocks per cloud
    const int qbase = (blockIdx.x & 127) * QPB;
    const int base  = cloud * S_;

    for (int r = tid; r < S_; r += NTK) {
        const float* p = pos + (size_t)(base + r) * 3;
        spos[r] = make_float4(p[0], p[1], p[2], 0.0f);
    }
    __syncthreads();

    const int s  = tid & 7;                 // slice: j = s (mod 8)
    const int qi = qbase + (tid >> 3);      // query within cloud
    const float4 pi = spos[qi];
    const float pix = pi.x, piy = pi.y, piz = pi.z;

    double key[16];
#pragma unroll
    for (int t = 0; t < 16; ++t)
        key[t] = __longlong_as_double(0x7FEFFFFFFFFFFFFFULL);  // > any real key

    const float4* sp = &spos[s];            // lane slice pointer, stride 8
    float4 buf[8];                          // software-pipelined chunk loads
#pragma unroll
    for (int u = 0; u < 8; ++u) buf[u] = sp[8 * u];

    int jlow = s;                           // local j of buf[0]
    for (int c = 0; c < 16; ++c) {          // 16 chunks x 8 candidates = 128
        double nk[8];
#pragma unroll
        for (int u = 0; u < 8; ++u) {
            // bit-exact numpy chain: no fma, (dx2+dy2)+dz2
            const float dx = __fsub_rn(pix, buf[u].x);
            const float dy = __fsub_rn(piy, buf[u].y);
            const float dz = __fsub_rn(piz, buf[u].z);
            const float d2 = __fadd_rn(
                __fadd_rn(__fmul_rn(dx, dx), __fmul_rn(dy, dy)),
                __fmul_rn(dz, dz));
            nk[u] = pack_key(d2, jlow + 8 * u);
        }
        if (c < 15) {                       // prefetch next chunk during sort
            sp += 64;
#pragma unroll
            for (int u = 0; u < 8; ++u) buf[u] = sp[8 * u];
        }
        jlow += 64;

        sort8(nk);
        // keep-16-smallest: INF-padded bitonic half-merge, then clean
#pragma unroll
        for (int t = 0; t < 8; ++t)
            key[8 + t] = fmin(key[8 + t], nk[7 - t]);
        clean16(key);
    }

    // butterfly merge of the 8 slice lists; afterwards ALL 8 lanes of a
    // group hold the identical ascending top-16 of the query.
#pragma unroll
    for (int r = 1; r <= 4; r <<= 1) {
        double nk[16];
#pragma unroll
        for (int t = 0; t < 16; ++t)
            nk[t] = __shfl_xor(key[15 - t], r, 64);  // reversed partner list
#pragma unroll
        for (int t = 0; t < 16; ++t)
            key[t] = fmin(key[t], nk[t]);            // stride-16 half-cleaner
        clean16(key);
    }

    // ---- fused epilogue: each group of 8 lanes emits its query's 16 rows ----
    const float4* x4 = (const float4*)x;
    const float4* W4 = (const float4*)Wm;   // W[10][32]: row = 8 float4
    float4 wcol[10];
#pragma unroll
    for (int m = 0; m < 10; ++m) wcol[m] = W4[m * 8 + s];
    const float4 bb = ((const float4*)bv)[s];

    float4* orow = (float4*)out + (size_t)(base + qi) * (K_ * 16);
#pragma unroll
    for (int k = 0; k < 16; ++k) {
        const int jl = (int)(u32)__double_as_longlong(key[k]);   // local j
        // channels 4s..4s+3 of x_j (lane-coalesced 128B per group)
        const float4 xj = x4[(size_t)(base + jl) * 8 + s];
        // enc channels 32+4s..32+4s+3
        const float4 pj = spos[jl];                              // broadcast
        const float rx = pix - pj.x, ry = piy - pj.y, rz = piz - pj.z;
        const float dist = sqrtf(rx * rx + ry * ry + rz * rz + 1e-12f);
        const float f[10] = {pix, piy, piz, pj.x, pj.y, pj.z, rx, ry, rz, dist};
        float4 acc = bb;
#pragma unroll
        for (int m = 0; m < 10; ++m) {
            acc.x = fmaf(f[m], wcol[m].x, acc.x);
            acc.y = fmaf(f[m], wcol[m].y, acc.y);
            acc.z = fmaf(f[m], wcol[m].z, acc.z);
            acc.w = fmaf(f[m], wcol[m].w, acc.w);
        }
        acc.x = fmaxf(acc.x, 0.0f);
        acc.y = fmaxf(acc.y, 0.0f);
        acc.z = fmaxf(acc.z, 0.0f);
        acc.w = fmaxf(acc.w, 0.0f);
        orow[k * 16 + s]     = xj;
        orow[k * 16 + 8 + s] = acc;
    }
}

extern "C" void kernel_launch(void* const* d_in, const int* in_sizes, int n_in,
                              void* d_out, int out_size, void* d_ws, size_t ws_size,
                              hipStream_t stream) {
    const float* x   = (const float*)d_in[0];
    const float* pos = (const float*)d_in[1];
    // d_in[2] = batch (unused: equal-size contiguous clouds)
    const float* Wm  = (const float*)d_in[3];
    const float* bv  = (const float*)d_in[4];
    float* out = (float*)d_out;

    knn_fused<<<B_ * 128, NTK, 0, stream>>>(pos, x, Wm, bv, out);
}

// Round 8
// 47.864 us; speedup vs baseline: 1.2109x; 1.0709x over previous
//
#include <hip/hip_runtime.h>

typedef unsigned long long u64;
typedef unsigned int u32;
typedef float f32x4 __attribute__((ext_vector_type(4)));

#define B_  32
#define S_  1024
#define K_  16
#define NTK 256     // threads/block (4 waves)
#define LPQ 16      // lanes per query
#define QPB 16      // queries per block (NTK/LPQ)

// key = double whose bit pattern is (d2_f32_bits << 32) | j.
// d2 >= 0 -> high word in [0, 0x7F7FFFFF] -> positive finite double,
// so IEEE fmin/fmax (v_min_f64/v_max_f64) order keys exactly as u64.
__device__ __forceinline__ double pack_key(float d2, int j) {
    return __longlong_as_double(((u64)__float_as_uint(d2) << 32) | (u32)j);
}

// ascending compare-exchange: 2 VALU instrs
__device__ __forceinline__ void ce(double& a, double& b) {
    const double lo = fmin(a, b);
    const double hi = fmax(a, b);
    a = lo; b = hi;
}

// Batcher odd-even mergesort of 8 keys, 19 CE, depth 6, ascending
__device__ __forceinline__ void sort8(double (&k)[8]) {
    ce(k[0], k[1]); ce(k[2], k[3]); ce(k[4], k[5]); ce(k[6], k[7]);
    ce(k[0], k[2]); ce(k[1], k[3]); ce(k[4], k[6]); ce(k[5], k[7]);
    ce(k[1], k[2]); ce(k[5], k[6]);
    ce(k[0], k[4]); ce(k[1], k[5]); ce(k[2], k[6]); ce(k[3], k[7]);
    ce(k[2], k[4]); ce(k[3], k[5]);
    ce(k[1], k[2]); ce(k[3], k[4]); ce(k[5], k[6]);
}

// clean a bitonic 16-sequence into ascending order (4 stages, 32 CE)
__device__ __forceinline__ void clean16(double (&k)[16]) {
#pragma unroll
    for (int str = 8; str > 0; str >>= 1) {
#pragma unroll
        for (int t = 0; t < 16; ++t) {
            const int p = t ^ str;
            if (p > t) ce(k[t], k[p]);
        }
    }
}

__device__ __forceinline__ void nt_store4(float4 v, float4* p) {
    f32x4 w;
    w.x = v.x; w.y = v.y; w.z = v.z; w.w = v.w;
    __builtin_nontemporal_store(w, (f32x4*)p);
}

__global__ __launch_bounds__(NTK, 4)
void knn_fused(const float* __restrict__ pos, const float* __restrict__ x,
               const float* __restrict__ Wm, const float* __restrict__ bv,
               float* __restrict__ out) {
    __shared__ float4 spos[S_];             // 16 KB -> 4 blocks/CU (wave-limited)

    const int tid   = threadIdx.x;
    const int cloud = blockIdx.x >> 6;      // 64 blocks per cloud
    const int qbase = (blockIdx.x & 63) * QPB;
    const int base  = cloud * S_;

    for (int r = tid; r < S_; r += NTK) {
        const float* p = pos + (size_t)(base + r) * 3;
        spos[r] = make_float4(p[0], p[1], p[2], 0.0f);
    }
    __syncthreads();

    const int s  = tid & (LPQ - 1);         // slice: j = s (mod 16)
    const int qi = qbase + (tid >> 4);      // query within cloud
    const float4 pi = spos[qi];
    const float pix = pi.x, piy = pi.y, piz = pi.z;

    double key[16];
#pragma unroll
    for (int t = 0; t < 16; ++t)
        key[t] = __longlong_as_double(0x7FEFFFFFFFFFFFFFULL);  // > any real key

    const float4* sp = &spos[s];            // lane slice pointer, stride 16
    float4 buf[8];                          // software-pipelined chunk loads
#pragma unroll
    for (int u = 0; u < 8; ++u) buf[u] = sp[16 * u];

    int jlow = s;                           // local j of buf[0]
    for (int c = 0; c < 8; ++c) {           // 8 chunks x 8 candidates = 64
        double nk[8];
#pragma unroll
        for (int u = 0; u < 8; ++u) {
            // bit-exact numpy chain: no fma, (dx2+dy2)+dz2
            const float dx = __fsub_rn(pix, buf[u].x);
            const float dy = __fsub_rn(piy, buf[u].y);
            const float dz = __fsub_rn(piz, buf[u].z);
            const float d2 = __fadd_rn(
                __fadd_rn(__fmul_rn(dx, dx), __fmul_rn(dy, dy)),
                __fmul_rn(dz, dz));
            nk[u] = pack_key(d2, jlow + 16 * u);
        }
        if (c < 7) {                        // prefetch next chunk during sort
            sp += 128;
#pragma unroll
            for (int u = 0; u < 8; ++u) buf[u] = sp[16 * u];
        }
        jlow += 128;

        sort8(nk);
        // keep-16-smallest: INF-padded bitonic half-merge, then clean
#pragma unroll
        for (int t = 0; t < 8; ++t)
            key[8 + t] = fmin(key[8 + t], nk[7 - t]);
        clean16(key);
    }

    // butterfly merge of the 16 slice lists; afterwards ALL 16 lanes of a
    // group hold the identical ascending top-16 of the query.
#pragma unroll
    for (int r = 1; r <= 8; r <<= 1) {
        double nk[16];
#pragma unroll
        for (int t = 0; t < 16; ++t)
            nk[t] = __shfl_xor(key[15 - t], r, 64);  // reversed partner list
#pragma unroll
        for (int t = 0; t < 16; ++t)
            key[t] = fmin(key[t], nk[t]);            // stride-16 half-cleaner
        clean16(key);
    }

    // ---- fused epilogue: 16 lanes emit the query's 16 output rows ----
    // lane s<8: float4 slot s of x_j ; lane s>=8: enc float4 slot s-8
    float4* orow = (float4*)out + (size_t)(base + qi) * (K_ * 16);

    if (s < 8) {
        const float4* x4 = (const float4*)x;
#pragma unroll
        for (int k = 0; k < 16; ++k) {
            const int jl = (int)(u32)__double_as_longlong(key[k]);
            const float4 xj = x4[(size_t)(base + jl) * 8 + s];   // coalesced
            nt_store4(xj, &orow[k * 16 + s]);
        }
    } else {
        const int c4 = s - 8;               // enc float4 column 0..7
        const float4* W4 = (const float4*)Wm;   // W[10][32]: row = 8 float4
        float4 wcol[10];
#pragma unroll
        for (int m = 0; m < 10; ++m) wcol[m] = W4[m * 8 + c4];
        const float4 bb = ((const float4*)bv)[c4];
#pragma unroll
        for (int k = 0; k < 16; ++k) {
            const int jl = (int)(u32)__double_as_longlong(key[k]);
            const float4 pj = spos[jl];                          // broadcast
            const float rx = pix - pj.x, ry = piy - pj.y, rz = piz - pj.z;
            const float dist = sqrtf(rx * rx + ry * ry + rz * rz + 1e-12f);
            const float f[10] = {pix, piy, piz, pj.x, pj.y, pj.z, rx, ry, rz, dist};
            float4 acc = bb;
#pragma unroll
            for (int m = 0; m < 10; ++m) {
                acc.x = fmaf(f[m], wcol[m].x, acc.x);
                acc.y = fmaf(f[m], wcol[m].y, acc.y);
                acc.z = fmaf(f[m], wcol[m].z, acc.z);
                acc.w = fmaf(f[m], wcol[m].w, acc.w);
            }
            acc.x = fmaxf(acc.x, 0.0f);
            acc.y = fmaxf(acc.y, 0.0f);
            acc.z = fmaxf(acc.z, 0.0f);
            acc.w = fmaxf(acc.w, 0.0f);
            nt_store4(acc, &orow[k * 16 + 8 + c4]);
        }
    }
}

extern "C" void kernel_launch(void* const* d_in, const int* in_sizes, int n_in,
                              void* d_out, int out_size, void* d_ws, size_t ws_size,
                              hipStream_t stream) {
    const float* x   = (const float*)d_in[0];
    const float* pos = (const float*)d_in[1];
    // d_in[2] = batch (unused: equal-size contiguous clouds)
    const float* Wm  = (const float*)d_in[3];
    const float* bv  = (const float*)d_in[4];
    float* out = (float*)d_out;

    knn_fused<<<B_ * 64, NTK, 0, stream>>>(pos, x, Wm, bv, out);
}